// Round 2
// baseline (4998.274 us; speedup 1.0000x reference)
//
#include <hip/hip_runtime.h>
#include <math.h>

#define N_NODES 50000
#define N_EDGES 200000
#define N_GRAPHS 128

// ---------------- persistent private scratch (allocated at dlopen, NOT in kernel_launch) ----
static void* g_scratch = nullptr;
struct ScratchInit {
    ScratchInit() {
        // 448 MB — enough for the full workspace layout (~415 MB needed).
        if (hipMalloc(&g_scratch, (size_t)448 * 1024 * 1024) != hipSuccess) g_scratch = nullptr;
    }
};
static ScratchInit g_scratch_init;

// ---------------- zero a region (avoid hipMemsetAsync edge cases in capture) -------------
__global__ void k_zero(int* __restrict__ p, int n) {
    int i = blockIdx.x * 256 + threadIdx.x;
    if (i < n) p[i] = 0;
}

// ---------------- edge-weight MLP: (E,3) -> relu(64) -> 1 -> sigmoid ----------------
__global__ void k_edge_mlp(const float* __restrict__ ea, const float* __restrict__ w1,
                           const float* __restrict__ b1, const float* __restrict__ w2,
                           const float* __restrict__ b2, float* __restrict__ ew, int E) {
    int e = blockIdx.x * 256 + threadIdx.x;
    if (e >= E) return;
    float a0 = ea[e * 3 + 0], a1 = ea[e * 3 + 1], a2 = ea[e * 3 + 2];
    float acc = b2[0];
#pragma unroll
    for (int j = 0; j < 64; j++) {
        float h = fmaf(a0, w1[j], fmaf(a1, w1[64 + j], fmaf(a2, w1[128 + j], b1[j])));
        h = fmaxf(h, 0.0f);
        acc = fmaf(h, w2[j], acc);
    }
    ew[e] = 1.0f / (1.0f + expf(-acc));
}

// ---------------- degree accumulation + in-degree histogram ----------------
__global__ void k_deg(const int* __restrict__ dst, const float* __restrict__ ew,
                      float* __restrict__ degf, int* __restrict__ counts, int E) {
    int e = blockIdx.x * 256 + threadIdx.x;
    if (e >= E) return;
    unsigned d = (unsigned)dst[e];
    if (d >= N_NODES) return;   // defensive: bad index -> wrong result, not a fault
    atomicAdd(&degf[d], ew[e]);
    atomicAdd(&counts[d], 1);
}

// dis = 1/sqrt(deg+1); selfnorm = dis^2   (deg includes self-loop weight 1 => always > 0)
__global__ void k_dis(const float* __restrict__ degf, float* __restrict__ dis,
                      float* __restrict__ selfn, int n) {
    int i = blockIdx.x * 256 + threadIdx.x;
    if (i >= n) return;
    float d = degf[i] + 1.0f;
    float r = (float)(1.0 / sqrt((double)d));
    dis[i] = r;
    selfn[i] = r * r;
}

// ---------------- single-block exclusive scan: counts[N] -> row_ptr[N+1] ----------------
__global__ void k_scan(const int* __restrict__ counts, int* __restrict__ row_ptr, int n) {
    __shared__ int buf[1024];
    __shared__ int carry;
    int t = threadIdx.x;
    if (t == 0) { carry = 0; row_ptr[0] = 0; }
    __syncthreads();
    for (int base = 0; base < n; base += 1024) {
        int i = base + t;
        int v = (i < n) ? counts[i] : 0;
        buf[t] = v;
        __syncthreads();
        for (int offs = 1; offs < 1024; offs <<= 1) {
            int add = (t >= offs) ? buf[t - offs] : 0;
            __syncthreads();
            buf[t] += add;
            __syncthreads();
        }
        int incl = buf[t] + carry;
        if (i < n) row_ptr[i + 1] = incl;
        int total = buf[1023];
        __syncthreads();
        if (t == 0) carry += total;
        __syncthreads();
    }
}

// ---------------- scatter edges into CSR (by dst), fold norm computation ----------------
__global__ void k_scatter(const int* __restrict__ src, const int* __restrict__ dst,
                          const float* __restrict__ ew, const float* __restrict__ dis,
                          const int* __restrict__ row_ptr, int* __restrict__ cursor,
                          int* __restrict__ colsrc, float* __restrict__ normw, int E) {
    int e = blockIdx.x * 256 + threadIdx.x;
    if (e >= E) return;
    unsigned d = (unsigned)dst[e], s = (unsigned)src[e];
    if (d >= N_NODES || s >= N_NODES) return;
    int pos = row_ptr[d] + atomicAdd(&cursor[d], 1);
    if ((unsigned)pos >= N_EDGES) return;
    colsrc[pos] = (int)s;
    normw[pos] = dis[s] * ew[e] * dis[d];
}

// ---------------- per-graph node counts + tiny scan ----------------
__global__ void k_gcount(const int* __restrict__ batch, int* __restrict__ gcnt, int n) {
    int i = blockIdx.x * 256 + threadIdx.x;
    if (i >= n) return;
    unsigned b = (unsigned)batch[i];
    if (b < N_GRAPHS) atomicAdd(&gcnt[b], 1);
}

__global__ void k_gscan(const int* __restrict__ gcnt, int* __restrict__ gstart) {
    if (threadIdx.x == 0 && blockIdx.x == 0) {
        int s = 0;
        for (int g = 0; g < N_GRAPHS; g++) { gstart[g] = s; s += gcnt[g]; }
    }
}

// ---------------- fp32 tiled GEMM: C[M,N] = A[M,K] @ B[K,N] (+bias)(relu) ----------------
// 128x128 tile, 256 threads, 8x8 per thread, BK=8.
template <bool BIAS, bool RELU>
__launch_bounds__(256)
__global__ void gemm_tile(const float* __restrict__ A, const float* __restrict__ B,
                          const float* __restrict__ bias, float* __restrict__ C,
                          int M, int K, int N) {
    constexpr int BM = 128, BN = 128, BK = 8, TM = 8, TN = 8;
    __shared__ float As[BK * BM];   // transposed: As[k][m]
    __shared__ float Bs[BK * BN];   // row-major:  Bs[k][n]
    int tid = threadIdx.x;
    int tx = tid % (BN / TN);   // 0..15
    int ty = tid / (BN / TN);   // 0..15
    int m0 = blockIdx.y * BM, n0 = blockIdx.x * BN;

    float acc[TM][TN] = {};

    int arow = tid / 2;              // 0..127
    int acol = (tid % 2) * 4;        // 0 or 4
    int brow = tid / 32;             // 0..7
    int bcol = (tid % 32) * 4;       // 0..124

    for (int k0 = 0; k0 < K; k0 += BK) {
        float4 av = make_float4(0.f, 0.f, 0.f, 0.f);
        int gr = m0 + arow;
        if (gr < M) av = *(const float4*)(A + (size_t)gr * K + k0 + acol);
        As[(acol + 0) * BM + arow] = av.x;
        As[(acol + 1) * BM + arow] = av.y;
        As[(acol + 2) * BM + arow] = av.z;
        As[(acol + 3) * BM + arow] = av.w;
        float4 bv = *(const float4*)(B + (size_t)(k0 + brow) * N + n0 + bcol);
        *(float4*)(Bs + brow * BN + bcol) = bv;
        __syncthreads();
#pragma unroll
        for (int kk = 0; kk < BK; kk++) {
            float a[TM], b[TN];
#pragma unroll
            for (int i = 0; i < TM; i += 4)
                *(float4*)(a + i) = *(const float4*)(As + kk * BM + ty * TM + i);
#pragma unroll
            for (int j = 0; j < TN; j += 4)
                *(float4*)(b + j) = *(const float4*)(Bs + kk * BN + tx * TN + j);
#pragma unroll
            for (int i = 0; i < TM; i++)
#pragma unroll
                for (int j = 0; j < TN; j++)
                    acc[i][j] = fmaf(a[i], b[j], acc[i][j]);
        }
        __syncthreads();
    }

#pragma unroll
    for (int i = 0; i < TM; i++) {
        int r = m0 + ty * TM + i;
        if (r >= M) continue;
#pragma unroll
        for (int j = 0; j < TN; j += 4) {
            int c = n0 + tx * TN + j;
            float4 v = *(float4*)(&acc[i][j]);
            if (BIAS) {
                const float4 bb = *(const float4*)(bias + c);
                v.x += bb.x; v.y += bb.y; v.z += bb.z; v.w += bb.w;
            }
            if (RELU) {
                v.x = fmaxf(v.x, 0.f); v.y = fmaxf(v.y, 0.f);
                v.z = fmaxf(v.z, 0.f); v.w = fmaxf(v.w, 0.f);
            }
            *(float4*)(C + (size_t)r * N + c) = v;
        }
    }
}

// ---------------- CSR aggregation: out[i] = relu(selfn[i]*xw[i] + sum_e w_e*xw[src_e] + b) ----
// F = 1024 floats = 256 float4; one block (256 threads) per node.
__global__ void k_agg(const float4* __restrict__ xw, float4* __restrict__ out,
                      const int* __restrict__ row_ptr, const int* __restrict__ colsrc,
                      const float* __restrict__ normw, const float* __restrict__ selfn,
                      const float* __restrict__ bias) {
    int i = blockIdx.x;
    int t = threadIdx.x;
    float sn = selfn[i];
    float4 v = xw[(size_t)i * 256 + t];
    float ax = sn * v.x, ay = sn * v.y, az = sn * v.z, aw = sn * v.w;
    int e = row_ptr[i], eend = row_ptr[i + 1];
    for (; e < eend; ++e) {
        unsigned s = (unsigned)colsrc[e];
        if (s >= N_NODES) continue;
        float w = normw[e];
        float4 u = xw[(size_t)s * 256 + t];
        ax = fmaf(w, u.x, ax); ay = fmaf(w, u.y, ay);
        az = fmaf(w, u.z, az); aw = fmaf(w, u.w, aw);
    }
    const float4 bb = ((const float4*)bias)[t];
    float4 r;
    r.x = fmaxf(ax + bb.x, 0.f);
    r.y = fmaxf(ay + bb.y, 0.f);
    r.z = fmaxf(az + bb.z, 0.f);
    r.w = fmaxf(aw + bb.w, 0.f);
    out[(size_t)i * 256 + t] = r;
}

// ---------------- mean-pool per graph (double accumulation) ----------------
__global__ void k_pool(const float4* __restrict__ h, const int* __restrict__ gstart,
                       const int* __restrict__ gcnt, float* __restrict__ pooled) {
    int g = blockIdx.x;
    int t = threadIdx.x;   // 256 threads x float4 = 1024 features
    int beg = gstart[g], cnt = gcnt[g];
    if (beg + cnt > N_NODES) cnt = N_NODES - beg;
    double a0 = 0, a1 = 0, a2 = 0, a3 = 0;
    for (int n = 0; n < cnt; n++) {
        float4 v = h[(size_t)(beg + n) * 256 + t];
        a0 += v.x; a1 += v.y; a2 += v.z; a3 += v.w;
    }
    float inv = 1.0f / fmaxf((float)gcnt[g], 1.0f);
    pooled[g * 1024 + t * 4 + 0] = (float)a0 * inv;
    pooled[g * 1024 + t * 4 + 1] = (float)a1 * inv;
    pooled[g * 1024 + t * 4 + 2] = (float)a2 * inv;
    pooled[g * 1024 + t * 4 + 3] = (float)a3 * inv;
}

// ---------------- small GEMM (M=128 rows): one thread per output, double accumulation ----
template <bool RELU>
__global__ void gemm_small(const float* __restrict__ A, const float* __restrict__ B,
                           const float* __restrict__ bias, float* __restrict__ C,
                           int K, int N) {
    int n = blockIdx.x * 256 + threadIdx.x;
    int m = blockIdx.y;
    if (n >= N) return;
    const float* a = A + (size_t)m * K;
    double acc = 0.0;
    for (int k = 0; k < K; k += 4) {
        acc += (double)a[k] * (double)B[(size_t)k * N + n];
        acc += (double)a[k + 1] * (double)B[(size_t)(k + 1) * N + n];
        acc += (double)a[k + 2] * (double)B[(size_t)(k + 2) * N + n];
        acc += (double)a[k + 3] * (double)B[(size_t)(k + 3) * N + n];
    }
    float r = (float)acc + bias[n];
    if (RELU) r = fmaxf(r, 0.0f);
    C[(size_t)m * N + n] = r;
}

extern "C" void kernel_launch(void* const* d_in, const int* in_sizes, int n_in,
                              void* d_out, int out_size, void* d_ws, size_t ws_size,
                              hipStream_t stream) {
    const float* x      = (const float*)d_in[0];
    const float* eattr  = (const float*)d_in[1];
    const int*   eidx   = (const int*)d_in[2];
    const int*   batch  = (const int*)d_in[3];
    const float* emb_w1 = (const float*)d_in[4];
    const float* emb_b1 = (const float*)d_in[5];
    const float* emb_w2 = (const float*)d_in[6];
    const float* emb_b2 = (const float*)d_in[7];
    const float* ep_w1  = (const float*)d_in[8];
    const float* ep_b1  = (const float*)d_in[9];
    const float* ep_w2  = (const float*)d_in[10];
    const float* ep_b2  = (const float*)d_in[11];
    const float* c6_w   = (const float*)d_in[12];
    const float* c6_b   = (const float*)d_in[13];
    const float* c7_w   = (const float*)d_in[14];
    const float* c7_b   = (const float*)d_in[15];
    const float* c8_w   = (const float*)d_in[16];
    const float* c8_b   = (const float*)d_in[17];
    const float* fc1_w  = (const float*)d_in[18];
    const float* fc1_b  = (const float*)d_in[19];
    const float* head_w = (const float*)d_in[20];
    const float* head_b = (const float*)d_in[21];
    float* out = (float*)d_out;

    const int* src = eidx;            // edge_index[0]
    const int* dst = eidx + N_EDGES;  // edge_index[1]

    // ---- workspace layout (floats), each region 256-element aligned ----
    size_t off = 0;
    auto lay = [&](size_t nelem) -> size_t {
        size_t p = off;
        off += (nelem + 255) & ~(size_t)255;
        return p;
    };
    size_t oX      = lay((size_t)N_NODES * 1024);
    size_t oY      = lay((size_t)N_NODES * 1024);
    size_t oew     = lay(N_EDGES);
    size_t odis    = lay(N_NODES);
    size_t oselfn  = lay(N_NODES);
    size_t onormw  = lay(N_EDGES);
    size_t opooled = lay((size_t)N_GRAPHS * 1024);
    size_t oz      = lay((size_t)N_GRAPHS * 2048);
    size_t zbeg = off;                 // zeroed region start
    size_t odegf   = lay(N_NODES);
    size_t ocounts = lay(N_NODES);
    size_t ocursor = lay(N_NODES);
    size_t ogcnt   = lay(N_GRAPHS);
    size_t zend = off;                 // zeroed region end
    size_t orowp   = lay(N_NODES + 1);
    size_t ocolsrc = lay(N_EDGES);
    size_t ogstart = lay(N_GRAPHS);
    size_t need_bytes = off * sizeof(float);

    // Prefer harness workspace if it is big enough; else fall back to the
    // dlopen-time private allocation. (ws_size is constant across calls, so
    // this branch does identical work on every call.)
    float* ws = (ws_size >= need_bytes) ? (float*)d_ws : (float*)g_scratch;

    float* X      = ws + oX;
    float* Y      = ws + oY;
    float* ew     = ws + oew;
    float* dis    = ws + odis;
    float* selfn  = ws + oselfn;
    float* normw  = ws + onormw;
    float* pooled = ws + opooled;
    float* z      = ws + oz;
    float* degf   = ws + odegf;
    int*   counts = (int*)(ws + ocounts);
    int*   cursor = (int*)(ws + ocursor);
    int*   gcnt   = (int*)(ws + ogcnt);
    int*   row_ptr= (int*)(ws + orowp);
    int*   colsrc = (int*)(ws + ocolsrc);
    int*   gstart = (int*)(ws + ogstart);

    dim3 blk(256);
    int egrid = (N_EDGES + 255) / 256;
    int ngrid = (N_NODES + 255) / 256;
    int mtiles = (N_NODES + 127) / 128;   // 391

    int nzero = (int)(zend - zbeg);
    k_zero<<<(nzero + 255) / 256, blk, 0, stream>>>((int*)(ws + zbeg), nzero);

    // edge weights + degrees + CSR build
    k_edge_mlp<<<egrid, blk, 0, stream>>>(eattr, ep_w1, ep_b1, ep_w2, ep_b2, ew, N_EDGES);
    k_deg<<<egrid, blk, 0, stream>>>(dst, ew, degf, counts, N_EDGES);
    k_dis<<<ngrid, blk, 0, stream>>>(degf, dis, selfn, N_NODES);
    k_scan<<<1, 1024, 0, stream>>>(counts, row_ptr, N_NODES);
    k_scatter<<<egrid, blk, 0, stream>>>(src, dst, ew, dis, row_ptr, cursor, colsrc, normw, N_EDGES);
    k_gcount<<<ngrid, blk, 0, stream>>>(batch, gcnt, N_NODES);
    k_gscan<<<1, 64, 0, stream>>>(gcnt, gstart);

    // embedding MLP: X(:, :512) = relu(x@W1+b1); Y(:, :512) = relu(X@W2+b2)
    gemm_tile<true, true><<<dim3(512 / 128, mtiles), blk, 0, stream>>>(x, emb_w1, emb_b1, X, N_NODES, 40, 512);
    gemm_tile<true, true><<<dim3(512 / 128, mtiles), blk, 0, stream>>>(X, emb_w2, emb_b2, Y, N_NODES, 512, 512);

    // conv6: xw = Y@c6_w -> X ; Y = relu(agg(X)+b)
    gemm_tile<false, false><<<dim3(1024 / 128, mtiles), blk, 0, stream>>>(Y, c6_w, nullptr, X, N_NODES, 512, 1024);
    k_agg<<<N_NODES, blk, 0, stream>>>((const float4*)X, (float4*)Y, row_ptr, colsrc, normw, selfn, c6_b);

    // conv7
    gemm_tile<false, false><<<dim3(1024 / 128, mtiles), blk, 0, stream>>>(Y, c7_w, nullptr, X, N_NODES, 1024, 1024);
    k_agg<<<N_NODES, blk, 0, stream>>>((const float4*)X, (float4*)Y, row_ptr, colsrc, normw, selfn, c7_b);

    // conv8
    gemm_tile<false, false><<<dim3(1024 / 128, mtiles), blk, 0, stream>>>(Y, c8_w, nullptr, X, N_NODES, 1024, 1024);
    k_agg<<<N_NODES, blk, 0, stream>>>((const float4*)X, (float4*)Y, row_ptr, colsrc, normw, selfn, c8_b);

    // mean pool -> pooled (128 x 1024)
    k_pool<<<N_GRAPHS, blk, 0, stream>>>((const float4*)Y, gstart, gcnt, pooled);

    // head: z = relu(pooled@fc1+b); out = z@head+b
    gemm_small<true><<<dim3((2048 + 255) / 256, N_GRAPHS), blk, 0, stream>>>(pooled, fc1_w, fc1_b, z, 1024, 2048);
    gemm_small<false><<<dim3((345 + 255) / 256, N_GRAPHS), blk, 0, stream>>>(z, head_w, head_b, out, 2048, 345);
}

// Round 3
// 2395.406 us; speedup vs baseline: 2.0866x; 2.0866x over previous
//
#include <hip/hip_runtime.h>
#include <math.h>

#define N_NODES 50000
#define N_EDGES 200000
#define N_GRAPHS 128
#define M_PAD 50048   // N_NODES rounded up to 128

typedef short s16x8 __attribute__((ext_vector_type(8)));
typedef float f32x4 __attribute__((ext_vector_type(4)));

// ---------------- persistent private scratch (allocated at dlopen, NOT in kernel_launch) ----
static void* g_scratch = nullptr;
struct ScratchInit {
    ScratchInit() {
        if (hipMalloc(&g_scratch, (size_t)704 * 1024 * 1024) != hipSuccess) g_scratch = nullptr;
    }
};
static ScratchInit g_scratch_init;

// ---------------- bf16 helpers ----------------
__device__ __forceinline__ unsigned short f2bf_rn(float x) {
    unsigned u = __float_as_uint(x);
    unsigned r = (u + 0x7FFFu + ((u >> 16) & 1u)) >> 16;
    return (unsigned short)r;
}
__device__ __forceinline__ float bf2f(unsigned short h) {
    return __uint_as_float(((unsigned)h) << 16);
}

__device__ __forceinline__ void gl_lds16(const void* g, void* l) {
    __builtin_amdgcn_global_load_lds((const __attribute__((address_space(1))) unsigned int*)g,
                                     (__attribute__((address_space(3))) unsigned int*)l, 16, 0, 0);
}

// ---------------- zero a region ----------------
__global__ void k_zero(int* __restrict__ p, int n) {
    int i = blockIdx.x * 256 + threadIdx.x;
    if (i < n) p[i] = 0;
}

// ---------------- edge-weight MLP ----------------
__global__ void k_edge_mlp(const float* __restrict__ ea, const float* __restrict__ w1,
                           const float* __restrict__ b1, const float* __restrict__ w2,
                           const float* __restrict__ b2, float* __restrict__ ew, int E) {
    int e = blockIdx.x * 256 + threadIdx.x;
    if (e >= E) return;
    float a0 = ea[e * 3 + 0], a1 = ea[e * 3 + 1], a2 = ea[e * 3 + 2];
    float acc = b2[0];
#pragma unroll
    for (int j = 0; j < 64; j++) {
        float h = fmaf(a0, w1[j], fmaf(a1, w1[64 + j], fmaf(a2, w1[128 + j], b1[j])));
        h = fmaxf(h, 0.0f);
        acc = fmaf(h, w2[j], acc);
    }
    ew[e] = 1.0f / (1.0f + expf(-acc));
}

// ---------------- degree + histogram ----------------
__global__ void k_deg(const int* __restrict__ dst, const float* __restrict__ ew,
                      float* __restrict__ degf, int* __restrict__ counts, int E) {
    int e = blockIdx.x * 256 + threadIdx.x;
    if (e >= E) return;
    unsigned d = (unsigned)dst[e];
    if (d >= N_NODES) return;
    atomicAdd(&degf[d], ew[e]);
    atomicAdd(&counts[d], 1);
}

__global__ void k_dis(const float* __restrict__ degf, float* __restrict__ dis,
                      float* __restrict__ selfn, int n) {
    int i = blockIdx.x * 256 + threadIdx.x;
    if (i >= n) return;
    float d = degf[i] + 1.0f;
    float r = (float)(1.0 / sqrt((double)d));
    dis[i] = r;
    selfn[i] = r * r;
}

// ---------------- single-block scan ----------------
__global__ void k_scan(const int* __restrict__ counts, int* __restrict__ row_ptr, int n) {
    __shared__ int buf[1024];
    __shared__ int carry;
    int t = threadIdx.x;
    if (t == 0) { carry = 0; row_ptr[0] = 0; }
    __syncthreads();
    for (int base = 0; base < n; base += 1024) {
        int i = base + t;
        int v = (i < n) ? counts[i] : 0;
        buf[t] = v;
        __syncthreads();
        for (int offs = 1; offs < 1024; offs <<= 1) {
            int add = (t >= offs) ? buf[t - offs] : 0;
            __syncthreads();
            buf[t] += add;
            __syncthreads();
        }
        int incl = buf[t] + carry;
        if (i < n) row_ptr[i + 1] = incl;
        int total = buf[1023];
        __syncthreads();
        if (t == 0) carry += total;
        __syncthreads();
    }
}

// ---------------- CSR scatter ----------------
__global__ void k_scatter(const int* __restrict__ src, const int* __restrict__ dst,
                          const float* __restrict__ ew, const float* __restrict__ dis,
                          const int* __restrict__ row_ptr, int* __restrict__ cursor,
                          int* __restrict__ colsrc, float* __restrict__ normw, int E) {
    int e = blockIdx.x * 256 + threadIdx.x;
    if (e >= E) return;
    unsigned d = (unsigned)dst[e], s = (unsigned)src[e];
    if (d >= N_NODES || s >= N_NODES) return;
    int pos = row_ptr[d] + atomicAdd(&cursor[d], 1);
    if ((unsigned)pos >= N_EDGES) return;
    colsrc[pos] = (int)s;
    normw[pos] = dis[s] * ew[e] * dis[d];
}

// ---------------- per-graph counts ----------------
__global__ void k_gcount(const int* __restrict__ batch, int* __restrict__ gcnt, int n) {
    int i = blockIdx.x * 256 + threadIdx.x;
    if (i >= n) return;
    unsigned b = (unsigned)batch[i];
    if (b < N_GRAPHS) atomicAdd(&gcnt[b], 1);
}

__global__ void k_gscan(const int* __restrict__ gcnt, int* __restrict__ gstart) {
    if (threadIdx.x == 0 && blockIdx.x == 0) {
        int s = 0;
        for (int g = 0; g < N_GRAPHS; g++) { gstart[g] = s; s += gcnt[g]; }
    }
}

// ---------------- weight split+transpose: W[K][N] f32 -> Bt_hi/Bt_lo[N][K] bf16 ----------------
__global__ void k_wsplit_t(const float* __restrict__ W, short* __restrict__ Bth,
                           short* __restrict__ Btl, int K, int N) {
    __shared__ float t[32][33];
    int tx = threadIdx.x % 32, ty = threadIdx.x / 32;   // 32 x 8
    int bx = blockIdx.x, by = blockIdx.y;
#pragma unroll
    for (int i = 0; i < 4; i++) {
        int k = by * 32 + ty + i * 8;
        t[ty + i * 8][tx] = W[(size_t)k * N + bx * 32 + tx];
    }
    __syncthreads();
#pragma unroll
    for (int i = 0; i < 4; i++) {
        int n = bx * 32 + ty + i * 8;
        int k = by * 32 + tx;
        float v = t[tx][ty + i * 8];
        unsigned short h = f2bf_rn(v);
        Bth[(size_t)n * K + k] = (short)h;
        Btl[(size_t)n * K + k] = (short)f2bf_rn(v - bf2f(h));
    }
}

// ---------------- fp32 tiled GEMM (emb1), epilogue writes split bf16 ----------------
__launch_bounds__(256)
__global__ void gemm_tile_split(const float* __restrict__ A, const float* __restrict__ B,
                                const float* __restrict__ bias, short* __restrict__ Chi,
                                short* __restrict__ Clo, int M, int K, int N) {
    constexpr int BM = 128, BN = 128, BK = 8, TM = 8, TN = 8;
    __shared__ float As[BK * BM];
    __shared__ float Bs[BK * BN];
    int tid = threadIdx.x;
    int tx = tid % (BN / TN);
    int ty = tid / (BN / TN);
    int m0 = blockIdx.y * BM, n0 = blockIdx.x * BN;
    float acc[TM][TN] = {};
    int arow = tid / 2;
    int acol = (tid % 2) * 4;
    int brow = tid / 32;
    int bcol = (tid % 32) * 4;
    for (int k0 = 0; k0 < K; k0 += BK) {
        float4 av = make_float4(0.f, 0.f, 0.f, 0.f);
        int gr = m0 + arow;
        if (gr < M) av = *(const float4*)(A + (size_t)gr * K + k0 + acol);
        As[(acol + 0) * BM + arow] = av.x;
        As[(acol + 1) * BM + arow] = av.y;
        As[(acol + 2) * BM + arow] = av.z;
        As[(acol + 3) * BM + arow] = av.w;
        float4 bv = *(const float4*)(B + (size_t)(k0 + brow) * N + n0 + bcol);
        *(float4*)(Bs + brow * BN + bcol) = bv;
        __syncthreads();
#pragma unroll
        for (int kk = 0; kk < BK; kk++) {
            float a[TM], b[TN];
#pragma unroll
            for (int i = 0; i < TM; i += 4)
                *(float4*)(a + i) = *(const float4*)(As + kk * BM + ty * TM + i);
#pragma unroll
            for (int j = 0; j < TN; j += 4)
                *(float4*)(b + j) = *(const float4*)(Bs + kk * BN + tx * TN + j);
#pragma unroll
            for (int i = 0; i < TM; i++)
#pragma unroll
                for (int j = 0; j < TN; j++)
                    acc[i][j] = fmaf(a[i], b[j], acc[i][j]);
        }
        __syncthreads();
    }
#pragma unroll
    for (int i = 0; i < TM; i++) {
        int r = m0 + ty * TM + i;
        if (r >= M) continue;
#pragma unroll
        for (int j = 0; j < TN; j += 4) {
            int c = n0 + tx * TN + j;
            short4 hv, lv;
            float vv[4];
#pragma unroll
            for (int q = 0; q < 4; q++) {
                float v = acc[i][j + q] + bias[c + q];
                vv[q] = fmaxf(v, 0.f);
            }
            hv.x = (short)f2bf_rn(vv[0]); hv.y = (short)f2bf_rn(vv[1]);
            hv.z = (short)f2bf_rn(vv[2]); hv.w = (short)f2bf_rn(vv[3]);
            lv.x = (short)f2bf_rn(vv[0] - bf2f(hv.x));
            lv.y = (short)f2bf_rn(vv[1] - bf2f(hv.y));
            lv.z = (short)f2bf_rn(vv[2] - bf2f(hv.z));
            lv.w = (short)f2bf_rn(vv[3] - bf2f(hv.w));
            *(short4*)(Chi + (size_t)r * N + c) = hv;
            *(short4*)(Clo + (size_t)r * N + c) = lv;
        }
    }
}

// ---------------- bf16x3 MFMA GEMM ----------------
// A (M_PAD x K) as hi/lo bf16, B^T (N x K) as hi/lo bf16.  C = A@B fp32.
// EPI 0: plain f32 C.  EPI 1: +bias, relu, write split bf16 (Chi/Clo).
// 128x128 tile, BK=32, 4 waves in 2x2, each wave 4x4 tiles of 16x16x32 MFMA, 3 products.
template <int EPI>
__launch_bounds__(256)
__global__ void gemm_mf(const short* __restrict__ Ah, const short* __restrict__ Al,
                        const short* __restrict__ Bh, const short* __restrict__ Bl,
                        const float* __restrict__ bias, float* __restrict__ C,
                        short* __restrict__ Chi, short* __restrict__ Clo,
                        int M, int K, int N) {
    __shared__ short lds[4 * 4096];
    short* lA_h = lds;
    short* lA_l = lds + 4096;
    short* lB_h = lds + 8192;
    short* lB_l = lds + 12288;
    int tid = threadIdx.x, lane = tid & 63, wave = tid >> 6;
    int wm = wave >> 1, wn = wave & 1;
    int q4 = lane >> 4, l15 = lane & 15;
    int m0 = blockIdx.y * 128, n0 = blockIdx.x * 128;
    f32x4 acc[4][4] = {};
    const short* gbase0 = Ah;
    const short* gbase1 = Al;
    const short* gbase2 = Bh;
    const short* gbase3 = Bl;

    for (int k0 = 0; k0 < K; k0 += 32) {
        __syncthreads();
#pragma unroll
        for (int it = 0; it < 8; ++it) {
            int arr = it >> 1;
            int ca = ((it & 1) << 8) + tid;          // chunk within array, 0..511
            int r = ca >> 2, slot = ca & 3;
            int q = slot ^ ((r >> 1) & 3);           // xor-swizzle: conflict-free frag reads
            int grow = (arr < 2) ? (m0 + r) : (n0 + r);
            const short* gb = (arr == 0) ? gbase0 : (arr == 1) ? gbase1 : (arr == 2) ? gbase2 : gbase3;
            const short* g = gb + (size_t)grow * K + k0 + q * 8;
            int chunk_base = ((it & 1) << 8) + (wave << 6);   // wave-uniform
            short* l = lds + arr * 4096 + chunk_base * 8;
            gl_lds16(g, l);
        }
        __syncthreads();
        s16x8 a_h[4], a_l[4], b_h[4], b_l[4];
#pragma unroll
        for (int t = 0; t < 4; ++t) {
            int rA = wm * 64 + t * 16 + l15;
            int pA = rA * 4 + (q4 ^ ((rA >> 1) & 3));
            a_h[t] = *(const s16x8*)(lA_h + pA * 8);
            a_l[t] = *(const s16x8*)(lA_l + pA * 8);
            int rB = wn * 64 + t * 16 + l15;
            int pB = rB * 4 + (q4 ^ ((rB >> 1) & 3));
            b_h[t] = *(const s16x8*)(lB_h + pB * 8);
            b_l[t] = *(const s16x8*)(lB_l + pB * 8);
        }
#pragma unroll
        for (int tm = 0; tm < 4; ++tm)
#pragma unroll
            for (int tn = 0; tn < 4; ++tn) {
                acc[tm][tn] = __builtin_amdgcn_mfma_f32_16x16x32_bf16(a_h[tm], b_h[tn], acc[tm][tn], 0, 0, 0);
                acc[tm][tn] = __builtin_amdgcn_mfma_f32_16x16x32_bf16(a_h[tm], b_l[tn], acc[tm][tn], 0, 0, 0);
                acc[tm][tn] = __builtin_amdgcn_mfma_f32_16x16x32_bf16(a_l[tm], b_h[tn], acc[tm][tn], 0, 0, 0);
            }
    }
    // epilogue: C/D layout col=lane&15, row=(lane>>4)*4+reg
#pragma unroll
    for (int tm = 0; tm < 4; ++tm) {
#pragma unroll
        for (int tn = 0; tn < 4; ++tn) {
            int col = n0 + wn * 64 + tn * 16 + l15;
#pragma unroll
            for (int r = 0; r < 4; ++r) {
                int row = m0 + wm * 64 + tm * 16 + q4 * 4 + r;
                if (row < M) {
                    float v = acc[tm][tn][r];
                    if (EPI == 0) {
                        C[(size_t)row * N + col] = v;
                    } else {
                        v += bias[col];
                        v = fmaxf(v, 0.f);
                        unsigned short h = f2bf_rn(v);
                        Chi[(size_t)row * N + col] = (short)h;
                        Clo[(size_t)row * N + col] = (short)f2bf_rn(v - bf2f(h));
                    }
                }
            }
        }
    }
}

// ---------------- CSR aggregation over f32 X; epilogue writes split bf16 or f32 ----------------
template <bool SPLIT>
__global__ void k_agg(const float4* __restrict__ xw, float4* __restrict__ out,
                      short* __restrict__ Yhi, short* __restrict__ Ylo,
                      const int* __restrict__ row_ptr, const int* __restrict__ colsrc,
                      const float* __restrict__ normw, const float* __restrict__ selfn,
                      const float* __restrict__ bias) {
    int i = blockIdx.x;
    int t = threadIdx.x;
    float sn = selfn[i];
    float4 v = xw[(size_t)i * 256 + t];
    float ax = sn * v.x, ay = sn * v.y, az = sn * v.z, aw = sn * v.w;
    int e = row_ptr[i], eend = row_ptr[i + 1];
    for (; e < eend; ++e) {
        unsigned s = (unsigned)colsrc[e];
        if (s >= N_NODES) continue;
        float w = normw[e];
        float4 u = xw[(size_t)s * 256 + t];
        ax = fmaf(w, u.x, ax); ay = fmaf(w, u.y, ay);
        az = fmaf(w, u.z, az); aw = fmaf(w, u.w, aw);
    }
    const float4 bb = ((const float4*)bias)[t];
    float4 r;
    r.x = fmaxf(ax + bb.x, 0.f);
    r.y = fmaxf(ay + bb.y, 0.f);
    r.z = fmaxf(az + bb.z, 0.f);
    r.w = fmaxf(aw + bb.w, 0.f);
    if (SPLIT) {
        short4 hv, lv;
        hv.x = (short)f2bf_rn(r.x); hv.y = (short)f2bf_rn(r.y);
        hv.z = (short)f2bf_rn(r.z); hv.w = (short)f2bf_rn(r.w);
        lv.x = (short)f2bf_rn(r.x - bf2f(hv.x));
        lv.y = (short)f2bf_rn(r.y - bf2f(hv.y));
        lv.z = (short)f2bf_rn(r.z - bf2f(hv.z));
        lv.w = (short)f2bf_rn(r.w - bf2f(hv.w));
        *(short4*)(Yhi + (size_t)i * 1024 + t * 4) = hv;
        *(short4*)(Ylo + (size_t)i * 1024 + t * 4) = lv;
    } else {
        out[(size_t)i * 256 + t] = r;
    }
}

// ---------------- mean-pool (double accumulation) ----------------
__global__ void k_pool(const float4* __restrict__ h, const int* __restrict__ gstart,
                       const int* __restrict__ gcnt, float* __restrict__ pooled) {
    int g = blockIdx.x;
    int t = threadIdx.x;
    int beg = gstart[g], cnt = gcnt[g];
    if (beg + cnt > N_NODES) cnt = N_NODES - beg;
    double a0 = 0, a1 = 0, a2 = 0, a3 = 0;
    for (int n = 0; n < cnt; n++) {
        float4 v = h[(size_t)(beg + n) * 256 + t];
        a0 += v.x; a1 += v.y; a2 += v.z; a3 += v.w;
    }
    float inv = 1.0f / fmaxf((float)gcnt[g], 1.0f);
    pooled[g * 1024 + t * 4 + 0] = (float)a0 * inv;
    pooled[g * 1024 + t * 4 + 1] = (float)a1 * inv;
    pooled[g * 1024 + t * 4 + 2] = (float)a2 * inv;
    pooled[g * 1024 + t * 4 + 3] = (float)a3 * inv;
}

// ---------------- small GEMM (M=128), double accumulation ----------------
template <bool RELU>
__global__ void gemm_small(const float* __restrict__ A, const float* __restrict__ B,
                           const float* __restrict__ bias, float* __restrict__ C,
                           int K, int N) {
    int n = blockIdx.x * 256 + threadIdx.x;
    int m = blockIdx.y;
    if (n >= N) return;
    const float* a = A + (size_t)m * K;
    double acc = 0.0;
    for (int k = 0; k < K; k += 4) {
        acc += (double)a[k] * (double)B[(size_t)k * N + n];
        acc += (double)a[k + 1] * (double)B[(size_t)(k + 1) * N + n];
        acc += (double)a[k + 2] * (double)B[(size_t)(k + 2) * N + n];
        acc += (double)a[k + 3] * (double)B[(size_t)(k + 3) * N + n];
    }
    float r = (float)acc + bias[n];
    if (RELU) r = fmaxf(r, 0.0f);
    C[(size_t)m * N + n] = r;
}

extern "C" void kernel_launch(void* const* d_in, const int* in_sizes, int n_in,
                              void* d_out, int out_size, void* d_ws, size_t ws_size,
                              hipStream_t stream) {
    const float* x      = (const float*)d_in[0];
    const float* eattr  = (const float*)d_in[1];
    const int*   eidx   = (const int*)d_in[2];
    const int*   batch  = (const int*)d_in[3];
    const float* emb_w1 = (const float*)d_in[4];
    const float* emb_b1 = (const float*)d_in[5];
    const float* emb_w2 = (const float*)d_in[6];
    const float* emb_b2 = (const float*)d_in[7];
    const float* ep_w1  = (const float*)d_in[8];
    const float* ep_b1  = (const float*)d_in[9];
    const float* ep_w2  = (const float*)d_in[10];
    const float* ep_b2  = (const float*)d_in[11];
    const float* c6_w   = (const float*)d_in[12];
    const float* c6_b   = (const float*)d_in[13];
    const float* c7_w   = (const float*)d_in[14];
    const float* c7_b   = (const float*)d_in[15];
    const float* c8_w   = (const float*)d_in[16];
    const float* c8_b   = (const float*)d_in[17];
    const float* fc1_w  = (const float*)d_in[18];
    const float* fc1_b  = (const float*)d_in[19];
    const float* head_w = (const float*)d_in[20];
    const float* head_b = (const float*)d_in[21];
    float* out = (float*)d_out;

    const int* src = eidx;
    const int* dst = eidx + N_EDGES;

    // ---- workspace layout (bytes) ----
    size_t off = 0;
    auto lay = [&](size_t nbytes) -> size_t {
        size_t p = off;
        off += (nbytes + 255) & ~(size_t)255;
        return p;
    };
    size_t oX   = lay((size_t)M_PAD * 1024 * 4);   // f32 gemm output (gather source)
    size_t oP1  = lay((size_t)M_PAD * 1024 * 4);   // S3 hi+lo  OR  Y f32
    size_t oP2  = lay((size_t)M_PAD * 512 * 4);    // S1 hi+lo  OR  S4hi
    size_t oP3  = lay((size_t)M_PAD * 512 * 4);    // S2 hi+lo  OR  S4lo
    size_t oBt2 = lay((size_t)512 * 512 * 2 * 2);
    size_t oBt6 = lay((size_t)1024 * 512 * 2 * 2);
    size_t oBt7 = lay((size_t)1024 * 1024 * 2 * 2);
    size_t oBt8 = lay((size_t)1024 * 1024 * 2 * 2);
    size_t oew     = lay(N_EDGES * 4);
    size_t odis    = lay(N_NODES * 4);
    size_t oselfn  = lay(N_NODES * 4);
    size_t onormw  = lay(N_EDGES * 4);
    size_t opooled = lay((size_t)N_GRAPHS * 1024 * 4);
    size_t oz      = lay((size_t)N_GRAPHS * 2048 * 4);
    size_t zbeg = off;
    size_t odegf   = lay(N_NODES * 4);
    size_t ocounts = lay(N_NODES * 4);
    size_t ocursor = lay(N_NODES * 4);
    size_t ogcnt   = lay(N_GRAPHS * 4);
    size_t zend = off;
    size_t orowp   = lay((N_NODES + 1) * 4);
    size_t ocolsrc = lay(N_EDGES * 4);
    size_t ogstart = lay(N_GRAPHS * 4);
    size_t need_bytes = off;

    char* base = (ws_size >= need_bytes) ? (char*)d_ws : (char*)g_scratch;

    float* X      = (float*)(base + oX);
    short* S1h    = (short*)(base + oP2);
    short* S1l    = S1h + (size_t)M_PAD * 512;
    short* S2h    = (short*)(base + oP3);
    short* S2l    = S2h + (size_t)M_PAD * 512;
    short* S3h    = (short*)(base + oP1);
    short* S3l    = S3h + (size_t)M_PAD * 1024;
    short* S4h    = (short*)(base + oP2);   // M_PAD*1024 shorts, fills P2 exactly
    short* S4l    = (short*)(base + oP3);
    float* Y      = (float*)(base + oP1);
    short* Bt2h   = (short*)(base + oBt2);
    short* Bt2l   = Bt2h + (size_t)512 * 512;
    short* Bt6h   = (short*)(base + oBt6);
    short* Bt6l   = Bt6h + (size_t)1024 * 512;
    short* Bt7h   = (short*)(base + oBt7);
    short* Bt7l   = Bt7h + (size_t)1024 * 1024;
    short* Bt8h   = (short*)(base + oBt8);
    short* Bt8l   = Bt8h + (size_t)1024 * 1024;
    float* ew     = (float*)(base + oew);
    float* dis    = (float*)(base + odis);
    float* selfn  = (float*)(base + oselfn);
    float* normw  = (float*)(base + onormw);
    float* pooled = (float*)(base + opooled);
    float* z      = (float*)(base + oz);
    float* degf   = (float*)(base + odegf);
    int*   counts = (int*)(base + ocounts);
    int*   cursor = (int*)(base + ocursor);
    int*   gcnt   = (int*)(base + ogcnt);
    int*   row_ptr= (int*)(base + orowp);
    int*   colsrc = (int*)(base + ocolsrc);
    int*   gstart = (int*)(base + ogstart);

    dim3 blk(256);
    int egrid = (N_EDGES + 255) / 256;
    int ngrid = (N_NODES + 255) / 256;
    int mtiles = M_PAD / 128;   // 391

    int nzero = (int)((zend - zbeg) / 4);
    k_zero<<<(nzero + 255) / 256, blk, 0, stream>>>((int*)(base + zbeg), nzero);

    // edge weights + CSR build
    k_edge_mlp<<<egrid, blk, 0, stream>>>(eattr, ep_w1, ep_b1, ep_w2, ep_b2, ew, N_EDGES);
    k_deg<<<egrid, blk, 0, stream>>>(dst, ew, degf, counts, N_EDGES);
    k_dis<<<ngrid, blk, 0, stream>>>(degf, dis, selfn, N_NODES);
    k_scan<<<1, 1024, 0, stream>>>(counts, row_ptr, N_NODES);
    k_scatter<<<egrid, blk, 0, stream>>>(src, dst, ew, dis, row_ptr, cursor, colsrc, normw, N_EDGES);
    k_gcount<<<ngrid, blk, 0, stream>>>(batch, gcnt, N_NODES);
    k_gscan<<<1, 64, 0, stream>>>(gcnt, gstart);

    // weight split+transpose
    k_wsplit_t<<<dim3(512 / 32, 512 / 32), blk, 0, stream>>>(emb_w2, Bt2h, Bt2l, 512, 512);
    k_wsplit_t<<<dim3(1024 / 32, 512 / 32), blk, 0, stream>>>(c6_w, Bt6h, Bt6l, 512, 1024);
    k_wsplit_t<<<dim3(1024 / 32, 1024 / 32), blk, 0, stream>>>(c7_w, Bt7h, Bt7l, 1024, 1024);
    k_wsplit_t<<<dim3(1024 / 32, 1024 / 32), blk, 0, stream>>>(c8_w, Bt8h, Bt8l, 1024, 1024);

    // emb1 (fp32): S1 = split(relu(x@emb_w1+b1))
    gemm_tile_split<<<dim3(512 / 128, mtiles), blk, 0, stream>>>(x, emb_w1, emb_b1, S1h, S1l, N_NODES, 40, 512);

    // emb2 (bf16x3 MFMA): S2 = split(relu(S1@emb_w2+b2))
    gemm_mf<1><<<dim3(512 / 128, mtiles), blk, 0, stream>>>(S1h, S1l, Bt2h, Bt2l, emb_b2,
                                                            nullptr, S2h, S2l, N_NODES, 512, 512);

    // conv6: X = S2@c6_w ; S3 = split(relu(agg(X)+b))
    gemm_mf<0><<<dim3(1024 / 128, mtiles), blk, 0, stream>>>(S2h, S2l, Bt6h, Bt6l, nullptr,
                                                             X, nullptr, nullptr, N_NODES, 512, 1024);
    k_agg<true><<<N_NODES, blk, 0, stream>>>((const float4*)X, nullptr, S3h, S3l,
                                             row_ptr, colsrc, normw, selfn, c6_b);

    // conv7: X = S3@c7_w ; S4 = split(relu(agg(X)+b))
    gemm_mf<0><<<dim3(1024 / 128, mtiles), blk, 0, stream>>>(S3h, S3l, Bt7h, Bt7l, nullptr,
                                                             X, nullptr, nullptr, N_NODES, 1024, 1024);
    k_agg<true><<<N_NODES, blk, 0, stream>>>((const float4*)X, nullptr, S4h, S4l,
                                             row_ptr, colsrc, normw, selfn, c7_b);

    // conv8: X = S4@c8_w ; Y = relu(agg(X)+b)  (f32 for pooling)
    gemm_mf<0><<<dim3(1024 / 128, mtiles), blk, 0, stream>>>(S4h, S4l, Bt8h, Bt8l, nullptr,
                                                             X, nullptr, nullptr, N_NODES, 1024, 1024);
    k_agg<false><<<N_NODES, blk, 0, stream>>>((const float4*)X, (float4*)Y, nullptr, nullptr,
                                              row_ptr, colsrc, normw, selfn, c8_b);

    // pool + head (fp32/fp64-acc, tiny)
    k_pool<<<N_GRAPHS, blk, 0, stream>>>((const float4*)Y, gstart, gcnt, pooled);
    gemm_small<true><<<dim3((2048 + 255) / 256, N_GRAPHS), blk, 0, stream>>>(pooled, fc1_w, fc1_b, z, 1024, 2048);
    gemm_small<false><<<dim3((345 + 255) / 256, N_GRAPHS), blk, 0, stream>>>(z, head_w, head_b, out, 2048, 345);
}